// Round 4
// baseline (289.568 us; speedup 1.0000x reference)
//
#include <hip/hip_runtime.h>
#include <hip/hip_bf16.h>
#include <cstdint>
#include <math.h>

// Problem constants
#define B_DIM 2
#define T_SEQ 2048
#define C_DIM 1024
#define H_NUM 16
#define D_HEAD 64
#define M_ROWS (B_DIM * T_SEQ)      // 4096
#define N_QKV (3 * H_NUM * D_HEAD)  // 3072

using short8  = __attribute__((ext_vector_type(8))) short;
using short4v = __attribute__((ext_vector_type(4))) short;
using f32x4   = __attribute__((ext_vector_type(4))) float;

__device__ __forceinline__ short f2bf(float f) {
  union { __hip_bfloat16 h; short s; } u;
  u.h = __float2bfloat16(f);
  return u.s;
}

// async global->LDS, 16B per lane. LDS dest must be wave-uniform base + lane*16.
__device__ __forceinline__ void gld_lds16(short* lds, const short* g) {
  __builtin_amdgcn_global_load_lds(
      (const unsigned int __attribute__((address_space(1)))*)g,
      (unsigned int __attribute__((address_space(3)))*)lds, 16, 0, 0);
}

// ---------------------------------------------------------------------------
// Kernel 1: f32 -> bf16 cast (vectorized, 8 elems/thread)
// ---------------------------------------------------------------------------
__global__ __launch_bounds__(256) void cvt_f32_bf16(const float* __restrict__ in,
                                                    short* __restrict__ out, int n8) {
  int i = blockIdx.x * 256 + threadIdx.x;
  if (i >= n8) return;
  const float4* p = reinterpret_cast<const float4*>(in) + (size_t)i * 2;
  float4 a = p[0], b = p[1];
  short8 o;
  o[0] = f2bf(a.x); o[1] = f2bf(a.y); o[2] = f2bf(a.z); o[3] = f2bf(a.w);
  o[4] = f2bf(b.x); o[5] = f2bf(b.y); o[6] = f2bf(b.z); o[7] = f2bf(b.w);
  reinterpret_cast<short8*>(out)[i] = o;
}

// ---------------------------------------------------------------------------
// Kernel 2: pack Wq/Wk/Wv [H][C][D] f32 -> Wt [3*H*D][C] bf16 (transposed)
// ---------------------------------------------------------------------------
__global__ __launch_bounds__(256) void pack_w(const float* __restrict__ Wq,
                                              const float* __restrict__ Wk,
                                              const float* __restrict__ Wv,
                                              short* __restrict__ Wt) {
  int bid  = blockIdx.x;
  int proj = bid >> 8;
  int h    = (bid >> 4) & 15;
  int cb   = bid & 15;
  const float* W = (proj == 0) ? Wq : ((proj == 1) ? Wk : Wv);
  const float* src = W + ((size_t)h * C_DIM + (size_t)cb * 64) * D_HEAD;

  __shared__ float tile[64][65];
  int tid = threadIdx.x;

#pragma unroll
  for (int j = 0; j < 4; j++) {
    int flat = tid + j * 256;
    int c    = flat >> 4;
    int d4   = flat & 15;
    float4 v = reinterpret_cast<const float4*>(src + (size_t)c * D_HEAD)[d4];
    tile[c][d4 * 4 + 0] = v.x;
    tile[c][d4 * 4 + 1] = v.y;
    tile[c][d4 * 4 + 2] = v.z;
    tile[c][d4 * 4 + 3] = v.w;
  }
  __syncthreads();

  int d     = tid >> 2;
  int cpart = (tid & 3) * 16;
  short* dst = Wt + ((size_t)(proj * H_NUM + h) * D_HEAD + d) * C_DIM + cb * 64 + cpart;
  short8 o0, o1;
#pragma unroll
  for (int j = 0; j < 8; j++) {
    o0[j] = f2bf(tile[cpart + j][d]);
    o1[j] = f2bf(tile[cpart + 8 + j][d]);
  }
  *reinterpret_cast<short8*>(dst)     = o0;
  *reinterpret_cast<short8*>(dst + 8) = o1;
}

// ---------------------------------------------------------------------------
// GEMM: C[M,N] = A[M,K] @ Bt[N,K]^T, bf16 in, f32 accum.
// m97 structure: 128x128 tile, BK=32, linear LDS, global_load_lds width-16
// staging, 4 waves (2x2), 16x16x32 MFMA.
// MODE 0: epilogue scatters q (prescaled by 1/8), k as [B,H,T,D] bf16 and
//         v transposed [B,H,D,T]. MODE 1: adds bias, stores f32 [M][N].
// ---------------------------------------------------------------------------
template <int MODE>
__global__ __launch_bounds__(256) void gemm_bt(
    const short* __restrict__ A, const short* __restrict__ Bt,
    const float* __restrict__ bias,
    short* __restrict__ qb, short* __restrict__ kb, short* __restrict__ vtb,
    float* __restrict__ outb,
    int M, int N, int K) {
  constexpr int BK = 32;
  __shared__ short As[128 * BK];  // 8 KB, linear [row][32]
  __shared__ short Bs[128 * BK];

  int tid  = threadIdx.x;
  int lane = tid & 63;
  int wv   = tid >> 6;
  int q15  = lane & 15, g = lane >> 4;
  int ntn  = N >> 7;
  int bm   = blockIdx.x / ntn;
  int bn   = blockIdx.x % ntn;
  int row0 = bm << 7, col0 = bn << 7;
  int wm   = (wv >> 1) << 6;
  int wn   = (wv & 1) << 6;

  f32x4 acc[4][4];
#pragma unroll
  for (int i = 0; i < 4; i++)
#pragma unroll
    for (int j = 0; j < 4; j++) acc[i][j] = (f32x4){0.f, 0.f, 0.f, 0.f};

  const short* ag = A  + (size_t)(row0 + (tid >> 2)) * K + (tid & 3) * 8;
  const short* bg = Bt + (size_t)(col0 + (tid >> 2)) * K + (tid & 3) * 8;
  short* as = As + tid * 8;
  short* bs = Bs + tid * 8;
  const size_t gstep = (size_t)64 * K;

  for (int k0 = 0; k0 < K; k0 += BK) {
    __syncthreads();  // previous iteration's LDS reads done
    gld_lds16(as, ag);
    gld_lds16(as + 64 * BK, ag + gstep);
    gld_lds16(bs, bg);
    gld_lds16(bs + 64 * BK, bg + gstep);
    __syncthreads();  // compiler drains vmcnt(0) before s_barrier

    short8 af[4], bf[4];
#pragma unroll
    for (int mi = 0; mi < 4; mi++)
      af[mi] = *reinterpret_cast<const short8*>(&As[(wm + mi * 16 + q15) * BK + g * 8]);
#pragma unroll
    for (int ni = 0; ni < 4; ni++)
      bf[ni] = *reinterpret_cast<const short8*>(&Bs[(wn + ni * 16 + q15) * BK + g * 8]);
    __builtin_amdgcn_s_setprio(1);
#pragma unroll
    for (int mi = 0; mi < 4; mi++)
#pragma unroll
      for (int ni = 0; ni < 4; ni++)
        acc[mi][ni] = __builtin_amdgcn_mfma_f32_16x16x32_bf16(af[mi], bf[ni],
                                                              acc[mi][ni], 0, 0, 0);
    __builtin_amdgcn_s_setprio(0);
    ag += BK;
    bg += BK;
  }

  // epilogue: C/D layout: col = lane&15, row = (lane>>4)*4 + r
#pragma unroll
  for (int mi = 0; mi < 4; mi++) {
#pragma unroll
    for (int ni = 0; ni < 4; ni++) {
      int rb  = row0 + wm + mi * 16 + (g << 2);
      int col = col0 + wn + ni * 16 + q15;
      f32x4 v = acc[mi][ni];
      if (MODE == 0) {
        int proj = col >> 10;
        int hh   = (col >> 6) & (H_NUM - 1);
        int d    = col & (D_HEAD - 1);
        int b    = rb >> 11;
        int t    = rb & (T_SEQ - 1);
        if (proj < 2) {
          float scl = (proj == 0) ? 0.125f : 1.0f;  // fold 1/sqrt(D) into q
          short* dst = (proj == 0 ? qb : kb) +
                       ((size_t)(b * H_NUM + hh) * T_SEQ) * D_HEAD + d;
#pragma unroll
          for (int r = 0; r < 4; r++)
            dst[(size_t)(t + r) * D_HEAD] = f2bf(v[r] * scl);
        } else {
          short4v pk;
#pragma unroll
          for (int r = 0; r < 4; r++) pk[r] = f2bf(v[r]);
          short* dst = vtb + ((size_t)(b * H_NUM + hh) * D_HEAD + d) * T_SEQ + t;
          *reinterpret_cast<short4v*>(dst) = pk;
        }
      } else {
        float bb = bias[col];
#pragma unroll
        for (int r = 0; r < 4; r++)
          outb[(size_t)(rb + r) * N + col] = v[r] + bb;
      }
    }
  }
}

// ---------------------------------------------------------------------------
// Flash attention v4: swapped-operand (S^T = K·Q^T), registers only.
// 4 waves/block, 16 q-rows/wave (64 q/block) -> grid 1024 blocks = 4 waves/SIMD
// (TLP is the latency-hiding mechanism; __launch_bounds__(256,4) caps VGPR=128).
// Heavy-first XCD-local dispatch: 4 heads/XCD (KV 2MB < L2), qblk descending.
// ---------------------------------------------------------------------------
__global__ __launch_bounds__(256, 4) void attn_fwd(const short* __restrict__ qg,
                                                   const short* __restrict__ kg,
                                                   const short* __restrict__ vt,
                                                   short* __restrict__ ob) {
  constexpr float LOG2E = 1.44269504f;
  int bid  = blockIdx.x;
  int slot = bid >> 3;                  // 0..127
  int bh   = (bid & 7) * 4 + (slot & 3);
  int qblk = 31 - (slot >> 2);          // 0..31, heavy first
  int b    = bh >> 4;
  int h    = bh & 15;
  int tid  = threadIdx.x, lane = tid & 63, wv = tid >> 6;
  int q15  = lane & 15, g = lane >> 4;
  int qr   = qblk * 64 + wv * 16;  // wave's first q row

  const short* qp = qg + (size_t)bh * T_SEQ * D_HEAD;
  const short* kp = kg + (size_t)bh * T_SEQ * D_HEAD;
  const short* vp = vt + (size_t)bh * D_HEAD * T_SEQ;

  // Q fragment (B operand of S^T mfma): lane&15 = q, elems over d (prescaled)
  short8 qf[2];
#pragma unroll
  for (int kk = 0; kk < 2; kk++)
    qf[kk] = *reinterpret_cast<const short8*>(
        qp + (size_t)(qr + q15) * D_HEAD + kk * 32 + g * 8);

  f32x4 acc[4];  // O^T tiles [dt]: col=q, row=d
#pragma unroll
  for (int dt = 0; dt < 4; dt++) acc[dt] = (f32x4){0.f, 0.f, 0.f, 0.f};
  float m_ = -1e30f;
  float l_ = 0.f;

  // one 64-s chunk
  auto compute = [&](int s0, bool masked) {
    // K fragments for 4 s-tiles
    short8 kf[4][2];
#pragma unroll
    for (int st = 0; st < 4; st++) {
      const short* kr = kp + (size_t)(s0 + st * 16 + q15) * D_HEAD + g * 8;
      kf[st][0] = *reinterpret_cast<const short8*>(kr);
      kf[st][1] = *reinterpret_cast<const short8*>(kr + 32);
    }
    // V fragments issued early: consumed only after softmax
    short4v vf[4][4];  // [st][dt]
#pragma unroll
    for (int st = 0; st < 4; st++)
#pragma unroll
      for (int dt = 0; dt < 4; dt++)
        vf[st][dt] = *reinterpret_cast<const short4v*>(
            vp + (size_t)(dt * 16 + q15) * T_SEQ + s0 + st * 16 + g * 4);

    // S^T = K·Q^T: D[row=s][col=q]
    f32x4 sv[4];
    __builtin_amdgcn_s_setprio(1);
#pragma unroll
    for (int st = 0; st < 4; st++) {
      f32x4 s = (f32x4){0.f, 0.f, 0.f, 0.f};
      s = __builtin_amdgcn_mfma_f32_16x16x32_bf16(kf[st][0], qf[0], s, 0, 0, 0);
      s = __builtin_amdgcn_mfma_f32_16x16x32_bf16(kf[st][1], qf[1], s, 0, 0, 0);
      sv[st] = s;
    }
    __builtin_amdgcn_s_setprio(0);

    // causal mask (s <= q); Q prescaled so no scale mul
    if (masked) {
#pragma unroll
      for (int st = 0; st < 4; st++)
#pragma unroll
        for (int r = 0; r < 4; r++) {
          int sg = s0 + st * 16 + g * 4 + r;
          if (sg > qr + q15) sv[st][r] = -1e30f;
        }
    }

    // online softmax (lane-local chain + 2 shfl); fmaxf nests fuse to v_max3
    float mx = fmaxf(fmaxf(fmaxf(sv[0][0], sv[0][1]), fmaxf(sv[0][2], sv[0][3])),
                     fmaxf(fmaxf(sv[1][0], sv[1][1]), fmaxf(sv[1][2], sv[1][3])));
    mx = fmaxf(mx, fmaxf(fmaxf(fmaxf(sv[2][0], sv[2][1]), fmaxf(sv[2][2], sv[2][3])),
                         fmaxf(fmaxf(sv[3][0], sv[3][1]), fmaxf(sv[3][2], sv[3][3]))));
    mx = fmaxf(mx, __shfl_xor(mx, 16));
    mx = fmaxf(mx, __shfl_xor(mx, 32));
    float mnew = fmaxf(m_, mx);
    float sc   = __builtin_amdgcn_exp2f((m_ - mnew) * LOG2E);
    m_ = mnew;
    short4v pb[4];
    float ps = 0.f;
#pragma unroll
    for (int st = 0; st < 4; st++)
#pragma unroll
      for (int r = 0; r < 4; r++) {
        float p = __builtin_amdgcn_exp2f((sv[st][r] - mnew) * LOG2E);
        ps += p;
        pb[st][r] = f2bf(p);
      }
    ps += __shfl_xor(ps, 16);
    ps += __shfl_xor(ps, 32);
    l_ = l_ * sc + ps;
#pragma unroll
    for (int dt = 0; dt < 4; dt++) acc[dt] *= sc;

    // PV: O^T[d][q] += V^T[d][s] · P^T[s][q], 16-s tiles
    __builtin_amdgcn_s_setprio(1);
#pragma unroll
    for (int st = 0; st < 4; st++)
#pragma unroll
      for (int dt = 0; dt < 4; dt++) {
#if __has_builtin(__builtin_amdgcn_mfma_f32_16x16x16bf16_1k)
        acc[dt] = __builtin_amdgcn_mfma_f32_16x16x16bf16_1k(
            vf[st][dt], pb[st], acc[dt], 0, 0, 0);
#else
        short4v v4 = vf[st][dt];
        short4v p4 = pb[st];
        short8 az = (short8){v4[0], v4[1], v4[2], v4[3], 0, 0, 0, 0};
        short8 bz = (short8){p4[0], p4[1], p4[2], p4[3], 0, 0, 0, 0};
        acc[dt] =
            __builtin_amdgcn_mfma_f32_16x16x32_bf16(az, bz, acc[dt], 0, 0, 0);
#endif
      }
    __builtin_amdgcn_s_setprio(0);
  };

  for (int c = 0; c < qblk; c++) compute(c * 64, false);
  compute(qblk * 64, true);

  // epilogue: per-wave LDS transpose (no barrier needed) -> coalesced stores
  __shared__ short Ol[4][16][68];
  float inv = 1.0f / l_;
#pragma unroll
  for (int dt = 0; dt < 4; dt++)
#pragma unroll
    for (int r = 0; r < 4; r++)
      Ol[wv][q15][dt * 16 + g * 4 + r] = f2bf(acc[dt][r] * inv);
  __builtin_amdgcn_s_waitcnt(0);  // lgkmcnt(0): wave-local LDS visibility
  int row = lane >> 2, cb = (lane & 3) * 16;
  size_t base = ((size_t)(b * T_SEQ) + qr + row) * C_DIM + h * 64 + cb;
  *reinterpret_cast<short8*>(ob + base) =
      *reinterpret_cast<const short8*>(&Ol[wv][row][cb]);
  *reinterpret_cast<short8*>(ob + base + 8) =
      *reinterpret_cast<const short8*>(&Ol[wv][row][cb + 8]);
}

// ---------------------------------------------------------------------------
// Launch. Workspace layout (needs >= 40 MB):
//   [0, 8M)        xb   bf16 x cast            (reused as obuf after QKV GEMM)
//   [8M, 14.3M)    Wt   bf16 packed QKV weights [3072][1024]
//   [14M, 16M)     Wob  bf16 Wo [1024][1024]
//   [16M, 24M)     qb   bf16 [B,H,T,D]  (prescaled by 1/8)
//   [24M, 32M)     kb   bf16 [B,H,T,D]
//   [32M, 40M)     vtb  bf16 [B,H,D,T]
// ---------------------------------------------------------------------------
extern "C" void kernel_launch(void* const* d_in, const int* in_sizes, int n_in,
                              void* d_out, int out_size, void* d_ws, size_t ws_size,
                              hipStream_t stream) {
  const float* x  = (const float*)d_in[0];
  const float* Wq = (const float*)d_in[1];
  const float* Wk = (const float*)d_in[2];
  const float* Wv = (const float*)d_in[3];
  const float* Wo = (const float*)d_in[4];
  const float* bo = (const float*)d_in[5];
  float* out = (float*)d_out;

  char* ws = (char*)d_ws;
  short* xb   = (short*)(ws + 0);
  short* Wt   = (short*)(ws + 8388608);
  short* Wob  = (short*)(ws + 14680064);
  short* qb   = (short*)(ws + 16777216);
  short* kb   = (short*)(ws + 25165824);
  short* vtb  = (short*)(ws + 33554432);
  short* obuf = xb;  // reuse after QKV GEMM consumed xb

  cvt_f32_bf16<<<2048, 256, 0, stream>>>(x, xb, M_ROWS * C_DIM / 8);
  cvt_f32_bf16<<<512, 256, 0, stream>>>(Wo, Wob, C_DIM * C_DIM / 8);
  pack_w<<<768, 256, 0, stream>>>(Wq, Wk, Wv, Wt);

  gemm_bt<0><<<(M_ROWS / 128) * (N_QKV / 128), 256, 0, stream>>>(
      xb, Wt, nullptr, qb, kb, vtb, nullptr, M_ROWS, N_QKV, C_DIM);

  attn_fwd<<<B_DIM * H_NUM * (T_SEQ / 64), 256, 0, stream>>>(qb, kb, vtb, obuf);

  gemm_bt<1><<<(M_ROWS / 128) * (C_DIM / 128), 256, 0, stream>>>(
      obuf, Wob, bo, nullptr, nullptr, nullptr, out, M_ROWS, C_DIM, C_DIM);
}

// Round 5
// 142.577 us; speedup vs baseline: 2.0310x; 2.0310x over previous
//
#include <hip/hip_runtime.h>
#include <hip/hip_bf16.h>
#include <cstdint>
#include <math.h>

// Problem constants
#define B_DIM 2
#define T_SEQ 2048
#define C_DIM 1024
#define H_NUM 16
#define D_HEAD 64
#define M_ROWS (B_DIM * T_SEQ)      // 4096
#define N_QKV (3 * H_NUM * D_HEAD)  // 3072

using short8  = __attribute__((ext_vector_type(8))) short;
using short4v = __attribute__((ext_vector_type(4))) short;
using f32x4   = __attribute__((ext_vector_type(4))) float;

__device__ __forceinline__ short f2bf(float f) {
  union { __hip_bfloat16 h; short s; } u;
  u.h = __float2bfloat16(f);
  return u.s;
}

// async global->LDS, 16B per lane (proven m97 pattern: per-lane LDS ptr = base + lane*16B)
__device__ __forceinline__ void gld_lds16(short* lds, const short* g) {
  __builtin_amdgcn_global_load_lds(
      (const unsigned int __attribute__((address_space(1)))*)g,
      (unsigned int __attribute__((address_space(3)))*)lds, 16, 0, 0);
}

// ---------------------------------------------------------------------------
// Kernel 1: f32 -> bf16 cast (vectorized, 8 elems/thread)
// ---------------------------------------------------------------------------
__global__ __launch_bounds__(256) void cvt_f32_bf16(const float* __restrict__ in,
                                                    short* __restrict__ out, int n8) {
  int i = blockIdx.x * 256 + threadIdx.x;
  if (i >= n8) return;
  const float4* p = reinterpret_cast<const float4*>(in) + (size_t)i * 2;
  float4 a = p[0], b = p[1];
  short8 o;
  o[0] = f2bf(a.x); o[1] = f2bf(a.y); o[2] = f2bf(a.z); o[3] = f2bf(a.w);
  o[4] = f2bf(b.x); o[5] = f2bf(b.y); o[6] = f2bf(b.z); o[7] = f2bf(b.w);
  reinterpret_cast<short8*>(out)[i] = o;
}

// ---------------------------------------------------------------------------
// Kernel 2: pack Wq/Wk/Wv [H][C][D] f32 -> Wt [3*H*D][C] bf16 (transposed)
// ---------------------------------------------------------------------------
__global__ __launch_bounds__(256) void pack_w(const float* __restrict__ Wq,
                                              const float* __restrict__ Wk,
                                              const float* __restrict__ Wv,
                                              short* __restrict__ Wt) {
  int bid  = blockIdx.x;
  int proj = bid >> 8;
  int h    = (bid >> 4) & 15;
  int cb   = bid & 15;
  const float* W = (proj == 0) ? Wq : ((proj == 1) ? Wk : Wv);
  const float* src = W + ((size_t)h * C_DIM + (size_t)cb * 64) * D_HEAD;

  __shared__ float tile[64][65];
  int tid = threadIdx.x;

#pragma unroll
  for (int j = 0; j < 4; j++) {
    int flat = tid + j * 256;
    int c    = flat >> 4;
    int d4   = flat & 15;
    float4 v = reinterpret_cast<const float4*>(src + (size_t)c * D_HEAD)[d4];
    tile[c][d4 * 4 + 0] = v.x;
    tile[c][d4 * 4 + 1] = v.y;
    tile[c][d4 * 4 + 2] = v.z;
    tile[c][d4 * 4 + 3] = v.w;
  }
  __syncthreads();

  int d     = tid >> 2;
  int cpart = (tid & 3) * 16;
  short* dst = Wt + ((size_t)(proj * H_NUM + h) * D_HEAD + d) * C_DIM + cb * 64 + cpart;
  short8 o0, o1;
#pragma unroll
  for (int j = 0; j < 8; j++) {
    o0[j] = f2bf(tile[cpart + j][d]);
    o1[j] = f2bf(tile[cpart + 8 + j][d]);
  }
  *reinterpret_cast<short8*>(dst)     = o0;
  *reinterpret_cast<short8*>(dst + 8) = o1;
}

// ---------------------------------------------------------------------------
// GEMM: C[M,N] = A[M,K] @ Bt[N,K]^T, bf16 in, f32 accum.
// m97 structure: 128x128 tile, BK=32, linear LDS, global_load_lds width-16.
// ---------------------------------------------------------------------------
template <int MODE>
__global__ __launch_bounds__(256) void gemm_bt(
    const short* __restrict__ A, const short* __restrict__ Bt,
    const float* __restrict__ bias,
    short* __restrict__ qb, short* __restrict__ kb, short* __restrict__ vtb,
    float* __restrict__ outb,
    int M, int N, int K) {
  constexpr int BK = 32;
  __shared__ short As[128 * BK];
  __shared__ short Bs[128 * BK];

  int tid  = threadIdx.x;
  int lane = tid & 63;
  int wv   = tid >> 6;
  int q15  = lane & 15, g = lane >> 4;
  int ntn  = N >> 7;
  int bm   = blockIdx.x / ntn;
  int bn   = blockIdx.x % ntn;
  int row0 = bm << 7, col0 = bn << 7;
  int wm   = (wv >> 1) << 6;
  int wn   = (wv & 1) << 6;

  f32x4 acc[4][4];
#pragma unroll
  for (int i = 0; i < 4; i++)
#pragma unroll
    for (int j = 0; j < 4; j++) acc[i][j] = (f32x4){0.f, 0.f, 0.f, 0.f};

  const short* ag = A  + (size_t)(row0 + (tid >> 2)) * K + (tid & 3) * 8;
  const short* bg = Bt + (size_t)(col0 + (tid >> 2)) * K + (tid & 3) * 8;
  short* as = As + tid * 8;
  short* bs = Bs + tid * 8;
  const size_t gstep = (size_t)64 * K;

  for (int k0 = 0; k0 < K; k0 += BK) {
    __syncthreads();
    gld_lds16(as, ag);
    gld_lds16(as + 64 * BK, ag + gstep);
    gld_lds16(bs, bg);
    gld_lds16(bs + 64 * BK, bg + gstep);
    __syncthreads();

    short8 af[4], bf[4];
#pragma unroll
    for (int mi = 0; mi < 4; mi++)
      af[mi] = *reinterpret_cast<const short8*>(&As[(wm + mi * 16 + q15) * BK + g * 8]);
#pragma unroll
    for (int ni = 0; ni < 4; ni++)
      bf[ni] = *reinterpret_cast<const short8*>(&Bs[(wn + ni * 16 + q15) * BK + g * 8]);
    __builtin_amdgcn_s_setprio(1);
#pragma unroll
    for (int mi = 0; mi < 4; mi++)
#pragma unroll
      for (int ni = 0; ni < 4; ni++)
        acc[mi][ni] = __builtin_amdgcn_mfma_f32_16x16x32_bf16(af[mi], bf[ni],
                                                              acc[mi][ni], 0, 0, 0);
    __builtin_amdgcn_s_setprio(0);
    ag += BK;
    bg += BK;
  }

  // epilogue: C/D layout: col = lane&15, row = (lane>>4)*4 + r
#pragma unroll
  for (int mi = 0; mi < 4; mi++) {
#pragma unroll
    for (int ni = 0; ni < 4; ni++) {
      int rb  = row0 + wm + mi * 16 + (g << 2);
      int col = col0 + wn + ni * 16 + q15;
      f32x4 v = acc[mi][ni];
      if (MODE == 0) {
        int proj = col >> 10;
        int hh   = (col >> 6) & (H_NUM - 1);
        int d    = col & (D_HEAD - 1);
        int b    = rb >> 11;
        int t    = rb & (T_SEQ - 1);
        if (proj < 2) {
          float scl = (proj == 0) ? 0.125f : 1.0f;  // fold 1/sqrt(D) into q
          short* dst = (proj == 0 ? qb : kb) +
                       ((size_t)(b * H_NUM + hh) * T_SEQ) * D_HEAD + d;
#pragma unroll
          for (int r = 0; r < 4; r++)
            dst[(size_t)(t + r) * D_HEAD] = f2bf(v[r] * scl);
        } else {
          short4v pk;
#pragma unroll
          for (int r = 0; r < 4; r++) pk[r] = f2bf(v[r]);
          short* dst = vtb + ((size_t)(b * H_NUM + hh) * D_HEAD + d) * T_SEQ + t;
          *reinterpret_cast<short4v*>(dst) = pk;
        }
      } else {
        float bb = bias[col];
#pragma unroll
        for (int r = 0; r < 4; r++)
          outb[(size_t)(rb + r) * N + col] = v[r] + bb;
      }
    }
  }
}

// ---------------------------------------------------------------------------
// Flash attention v5: swapped-operand (S^T = K·Q^T); K/V chunks staged in LDS
// (shared by 4 waves, double-buffered, global_load_lds w=16, XOR-swizzled
// source + swizzled ds_read per rule #21). 2-phase schedule:
//   STAGE(next) -> ds_read(cur) -> compute -> __syncthreads().
// 4 waves x 32 q-rows (2 q-tiles), 512 blocks, heavy-first XCD-local dispatch.
// Defer-max (T13, THR=8) skips the O-rescale on most chunks.
// ---------------------------------------------------------------------------
__global__ __launch_bounds__(256) void attn_fwd(const short* __restrict__ qg,
                                                const short* __restrict__ kg,
                                                const short* __restrict__ vt,
                                                short* __restrict__ ob) {
  constexpr float LOG2E = 1.44269504f;
  int bid  = blockIdx.x;
  int slot = bid >> 3;                  // 0..63
  int bh   = (bid & 7) * 4 + (slot & 3);
  int qblk = 15 - (slot >> 2);          // 0..15, heavy first
  int b    = bh >> 4;
  int h    = bh & 15;
  int tid  = threadIdx.x, lane = tid & 63, wv = tid >> 6;
  int q15  = lane & 15, g = lane >> 4;
  int qr   = qblk * 128 + wv * 32;      // wave's first q row

  __shared__ short Kl[2][64 * 64];      // [s][d] swizzled, 8KB per buf
  __shared__ short Vl[2][64 * 64];      // [d][s] swizzled
  __shared__ short Ol[4][32][68];       // epilogue transpose

  const short* qp = qg + (size_t)bh * T_SEQ * D_HEAD;
  const short* kp = kg + (size_t)bh * T_SEQ * D_HEAD;
  const short* vp = vt + (size_t)bh * D_HEAD * T_SEQ;

  // --- staging geometry: lane covers (row r8 = lane>>3, stored colbyte scb).
  // LDS is written linearly (base + lane*16B); the SOURCE colbyte is
  // pre-swizzled so that data(row, cb) lands at LDS byte row*128 + (cb ^ ((row&7)<<4)).
  int r8    = lane >> 3;
  int gcb   = ((lane & 7) * 16) ^ (r8 << 4);  // source colbyte for this lane
  int srow0 = wv * 16;                        // wave stages rows [srow0, srow0+16)

  // --- fragment-read offsets (chunk-invariant, in shorts)
  int hh = (q15 & 7) << 4;
  int koff0 = ((0 * 64 + g * 16) ^ hh) >> 1;   // K cols 0..31 (bytes 0..63)
  int koff1 = ((1 * 64 + g * 16) ^ hh) >> 1;   // K cols 32..63
  int voff[4];
#pragma unroll
  for (int st = 0; st < 4; st++) voff[st] = ((st * 32 + g * 8) ^ hh) >> 1;

  // Q fragments (B operand of S^T mfma): lane&15 = q, elems over d (prescaled by 1/8)
  short8 qf[2][2];
#pragma unroll
  for (int qt = 0; qt < 2; qt++)
#pragma unroll
    for (int kk = 0; kk < 2; kk++)
      qf[qt][kk] = *reinterpret_cast<const short8*>(
          qp + (size_t)(qr + qt * 16 + q15) * D_HEAD + kk * 32 + g * 8);

  f32x4 acc[2][4];  // [qt][dt]: O^T, col=q, row=d
#pragma unroll
  for (int qt = 0; qt < 2; qt++)
#pragma unroll
    for (int dt = 0; dt < 4; dt++) acc[qt][dt] = (f32x4){0.f, 0.f, 0.f, 0.f};
  float m_[2] = {-1e30f, -1e30f};
  float l_[2] = {0.f, 0.f};

  int nch = qblk * 2 + 2;  // chunks covering s in [0, qblk*128+128)

  auto stage = [&](int c, int pb) {
    const short* ks = kp + (size_t)(c * 64 + srow0 + r8) * D_HEAD + (gcb >> 1);
    const short* vs = vp + (size_t)(srow0 + r8) * T_SEQ + c * 64 + (gcb >> 1);
    short* kd = &Kl[pb][srow0 * 64] + lane * 8;
    short* vd = &Vl[pb][srow0 * 64] + lane * 8;
    gld_lds16(kd, ks);
    gld_lds16(kd + 8 * 64, ks + (size_t)8 * D_HEAD);
    gld_lds16(vd, vs);
    gld_lds16(vd + 8 * 64, vs + (size_t)8 * T_SEQ);
  };

  stage(0, 0);
  __syncthreads();

  for (int c = 0; c < nch; ++c) {
    int s0 = c * 64;
    int pb = c & 1;
    if (c + 1 < nch) stage(c + 1, pb ^ 1);

    if (s0 <= qr + 31) {  // any unmasked row for this wave?
      bool masked = (s0 + 63 > qr);
      const short* Kb = &Kl[pb][0];
      const short* Vb = &Vl[pb][0];

      // K fragments from LDS (swizzled b128 reads, ~2-way banks)
      short8 kf[4][2];
#pragma unroll
      for (int st = 0; st < 4; st++) {
        int rbase = (st * 16 + q15) * 64;
        kf[st][0] = *reinterpret_cast<const short8*>(&Kb[rbase + koff0]);
        kf[st][1] = *reinterpret_cast<const short8*>(&Kb[rbase + koff1]);
      }

      // S^T = K·Q^T: D[row=s][col=q]
      f32x4 sv[2][4];
      __builtin_amdgcn_s_setprio(1);
#pragma unroll
      for (int st = 0; st < 4; st++)
#pragma unroll
        for (int qt = 0; qt < 2; qt++) {
          f32x4 s = (f32x4){0.f, 0.f, 0.f, 0.f};
          s = __builtin_amdgcn_mfma_f32_16x16x32_bf16(kf[st][0], qf[qt][0], s, 0, 0, 0);
          s = __builtin_amdgcn_mfma_f32_16x16x32_bf16(kf[st][1], qf[qt][1], s, 0, 0, 0);
          sv[qt][st] = s;
        }
      __builtin_amdgcn_s_setprio(0);

      // V fragments from LDS (issued here; consumed after softmax)
      short4v vf[4][4];  // [st][dt]
#pragma unroll
      for (int st = 0; st < 4; st++)
#pragma unroll
        for (int dt = 0; dt < 4; dt++)
          vf[st][dt] = *reinterpret_cast<const short4v*>(
              &Vb[(dt * 16 + q15) * 64 + voff[st]]);

      // causal mask (s <= q); Q prescaled so no scale mul
      if (masked) {
#pragma unroll
        for (int qt = 0; qt < 2; qt++)
#pragma unroll
          for (int st = 0; st < 4; st++)
#pragma unroll
            for (int r = 0; r < 4; r++) {
              int sg = s0 + st * 16 + g * 4 + r;
              if (sg > qr + qt * 16 + q15) sv[qt][st][r] = -1e30f;
            }
      }

      // online softmax per q-tile (lane-local + 2 shfl), defer-max (THR=8)
      short4v pbf[2][4];
#pragma unroll
      for (int qt = 0; qt < 2; qt++) {
        float mx = sv[qt][0][0];
#pragma unroll
        for (int st = 0; st < 4; st++)
#pragma unroll
          for (int r = 0; r < 4; r++) mx = fmaxf(mx, sv[qt][st][r]);
        mx = fmaxf(mx, __shfl_xor(mx, 16));
        mx = fmaxf(mx, __shfl_xor(mx, 32));
        if (!__all(mx <= m_[qt] + 8.0f)) {
          float mnew = fmaxf(m_[qt], mx);
          float sc   = __builtin_amdgcn_exp2f((m_[qt] - mnew) * LOG2E);
          m_[qt] = mnew;
          l_[qt] *= sc;
#pragma unroll
          for (int dt = 0; dt < 4; dt++) acc[qt][dt] *= sc;
        }
        float mcur = m_[qt];
        float ps = 0.f;
#pragma unroll
        for (int st = 0; st < 4; st++)
#pragma unroll
          for (int r = 0; r < 4; r++) {
            float p = __builtin_amdgcn_exp2f((sv[qt][st][r] - mcur) * LOG2E);
            ps += p;
            pbf[qt][st][r] = f2bf(p);
          }
        ps += __shfl_xor(ps, 16);
        ps += __shfl_xor(ps, 32);
        l_[qt] += ps;
      }

      // PV: O^T[d][q] += V^T[d][s] · P^T[s][q], 16-s tiles
      __builtin_amdgcn_s_setprio(1);
#pragma unroll
      for (int st = 0; st < 4; st++)
#pragma unroll
        for (int dt = 0; dt < 4; dt++)
#pragma unroll
          for (int qt = 0; qt < 2; qt++) {
#if __has_builtin(__builtin_amdgcn_mfma_f32_16x16x16bf16_1k)
            acc[qt][dt] = __builtin_amdgcn_mfma_f32_16x16x16bf16_1k(
                vf[st][dt], pbf[qt][st], acc[qt][dt], 0, 0, 0);
#else
            short4v v4 = vf[st][dt];
            short4v p4 = pbf[qt][st];
            short8 az = (short8){v4[0], v4[1], v4[2], v4[3], 0, 0, 0, 0};
            short8 bz = (short8){p4[0], p4[1], p4[2], p4[3], 0, 0, 0, 0};
            acc[qt][dt] =
                __builtin_amdgcn_mfma_f32_16x16x32_bf16(az, bz, acc[qt][dt], 0, 0, 0);
#endif
          }
      __builtin_amdgcn_s_setprio(0);
    }

    __syncthreads();  // drains vmcnt (staged next buf) + lgkm; all waves join
  }

  // epilogue: per-wave LDS transpose -> coalesced bf16 stores
#pragma unroll
  for (int qt = 0; qt < 2; qt++) {
    float inv = 1.0f / l_[qt];
#pragma unroll
    for (int dt = 0; dt < 4; dt++)
#pragma unroll
      for (int r = 0; r < 4; r++)
        Ol[wv][qt * 16 + q15][dt * 16 + g * 4 + r] = f2bf(acc[qt][dt][r] * inv);
  }
  __syncthreads();
  int row = lane >> 1, cb = (lane & 1) * 32;
  size_t base = ((size_t)(b * T_SEQ) + qr + row) * C_DIM + h * 64 + cb;
#pragma unroll
  for (int i = 0; i < 4; i++)
    *reinterpret_cast<short8*>(ob + base + i * 8) =
        *reinterpret_cast<const short8*>(&Ol[wv][row][cb + i * 8]);
}

// ---------------------------------------------------------------------------
// Launch. Workspace layout (needs >= 40 MB):
//   [0, 8M)        xb   bf16 x cast            (reused as obuf after QKV GEMM)
//   [8M, 14.3M)    Wt   bf16 packed QKV weights [3072][1024]
//   [14M, 16M)     Wob  bf16 Wo [1024][1024]
//   [16M, 24M)     qb   bf16 [B,H,T,D]  (prescaled by 1/8)
//   [24M, 32M)     kb   bf16 [B,H,T,D]
//   [32M, 40M)     vtb  bf16 [B,H,D,T]
// ---------------------------------------------------------------------------
extern "C" void kernel_launch(void* const* d_in, const int* in_sizes, int n_in,
                              void* d_out, int out_size, void* d_ws, size_t ws_size,
                              hipStream_t stream) {
  const float* x  = (const float*)d_in[0];
  const float* Wq = (const float*)d_in[1];
  const float* Wk = (const float*)d_in[2];
  const float* Wv = (const float*)d_in[3];
  const float* Wo = (const float*)d_in[4];
  const float* bo = (const float*)d_in[5];
  float* out = (float*)d_out;

  char* ws = (char*)d_ws;
  short* xb   = (short*)(ws + 0);
  short* Wt   = (short*)(ws + 8388608);
  short* Wob  = (short*)(ws + 14680064);
  short* qb   = (short*)(ws + 16777216);
  short* kb   = (short*)(ws + 25165824);
  short* vtb  = (short*)(ws + 33554432);
  short* obuf = xb;  // reuse after QKV GEMM consumed xb

  cvt_f32_bf16<<<2048, 256, 0, stream>>>(x, xb, M_ROWS * C_DIM / 8);
  cvt_f32_bf16<<<512, 256, 0, stream>>>(Wo, Wob, C_DIM * C_DIM / 8);
  pack_w<<<768, 256, 0, stream>>>(Wq, Wk, Wv, Wt);

  gemm_bt<0><<<(M_ROWS / 128) * (N_QKV / 128), 256, 0, stream>>>(
      xb, Wt, nullptr, qb, kb, vtb, nullptr, M_ROWS, N_QKV, C_DIM);

  attn_fwd<<<B_DIM * H_NUM * (T_SEQ / 128), 256, 0, stream>>>(qb, kb, vtb, obuf);

  gemm_bt<1><<<(M_ROWS / 128) * (C_DIM / 128), 256, 0, stream>>>(
      obuf, Wob, bo, nullptr, nullptr, nullptr, out, M_ROWS, C_DIM, C_DIM);
}

// Round 6
// 131.043 us; speedup vs baseline: 2.2097x; 1.0880x over previous
//
#include <hip/hip_runtime.h>
#include <hip/hip_bf16.h>
#include <cstdint>
#include <math.h>

// Problem constants
#define B_DIM 2
#define T_SEQ 2048
#define C_DIM 1024
#define H_NUM 16
#define D_HEAD 64
#define M_ROWS (B_DIM * T_SEQ)      // 4096
#define N_QKV (3 * H_NUM * D_HEAD)  // 3072

using short8  = __attribute__((ext_vector_type(8))) short;
using short4v = __attribute__((ext_vector_type(4))) short;
using f32x4   = __attribute__((ext_vector_type(4))) float;

__device__ __forceinline__ short f2bf(float f) {
  union { __hip_bfloat16 h; short s; } u;
  u.h = __float2bfloat16(f);
  return u.s;
}

// async global->LDS, 16B per lane (m97 pattern: per-lane LDS ptr = base + lane*16B)
__device__ __forceinline__ void gld_lds16(short* lds, const short* g) {
  __builtin_amdgcn_global_load_lds(
      (const unsigned int __attribute__((address_space(1)))*)g,
      (unsigned int __attribute__((address_space(3)))*)lds, 16, 0, 0);
}

// ---------------------------------------------------------------------------
// Kernel 1: f32 -> bf16 cast (vectorized, 8 elems/thread)
// ---------------------------------------------------------------------------
__global__ __launch_bounds__(256) void cvt_f32_bf16(const float* __restrict__ in,
                                                    short* __restrict__ out, int n8) {
  int i = blockIdx.x * 256 + threadIdx.x;
  if (i >= n8) return;
  const float4* p = reinterpret_cast<const float4*>(in) + (size_t)i * 2;
  float4 a = p[0], b = p[1];
  short8 o;
  o[0] = f2bf(a.x); o[1] = f2bf(a.y); o[2] = f2bf(a.z); o[3] = f2bf(a.w);
  o[4] = f2bf(b.x); o[5] = f2bf(b.y); o[6] = f2bf(b.z); o[7] = f2bf(b.w);
  reinterpret_cast<short8*>(out)[i] = o;
}

// ---------------------------------------------------------------------------
// Kernel 2: pack Wq/Wk/Wv [H][C][D] f32 -> Wt [3*H*D][C] bf16 (transposed)
// ---------------------------------------------------------------------------
__global__ __launch_bounds__(256) void pack_w(const float* __restrict__ Wq,
                                              const float* __restrict__ Wk,
                                              const float* __restrict__ Wv,
                                              short* __restrict__ Wt) {
  int bid  = blockIdx.x;
  int proj = bid >> 8;
  int h    = (bid >> 4) & 15;
  int cb   = bid & 15;
  const float* W = (proj == 0) ? Wq : ((proj == 1) ? Wk : Wv);
  const float* src = W + ((size_t)h * C_DIM + (size_t)cb * 64) * D_HEAD;

  __shared__ float tile[64][65];
  int tid = threadIdx.x;

#pragma unroll
  for (int j = 0; j < 4; j++) {
    int flat = tid + j * 256;
    int c    = flat >> 4;
    int d4   = flat & 15;
    float4 v = reinterpret_cast<const float4*>(src + (size_t)c * D_HEAD)[d4];
    tile[c][d4 * 4 + 0] = v.x;
    tile[c][d4 * 4 + 1] = v.y;
    tile[c][d4 * 4 + 2] = v.z;
    tile[c][d4 * 4 + 3] = v.w;
  }
  __syncthreads();

  int d     = tid >> 2;
  int cpart = (tid & 3) * 16;
  short* dst = Wt + ((size_t)(proj * H_NUM + h) * D_HEAD + d) * C_DIM + cb * 64 + cpart;
  short8 o0, o1;
#pragma unroll
  for (int j = 0; j < 8; j++) {
    o0[j] = f2bf(tile[cpart + j][d]);
    o1[j] = f2bf(tile[cpart + 8 + j][d]);
  }
  *reinterpret_cast<short8*>(dst)     = o0;
  *reinterpret_cast<short8*>(dst + 8) = o1;
}

// ---------------------------------------------------------------------------
// GEMM: C[M,N] = A[M,K] @ Bt[N,K]^T, bf16 in, f32 accum.
// m97 structure: 128x128 tile, BK=32, linear LDS, global_load_lds width-16.
// ---------------------------------------------------------------------------
template <int MODE>
__global__ __launch_bounds__(256) void gemm_bt(
    const short* __restrict__ A, const short* __restrict__ Bt,
    const float* __restrict__ bias,
    short* __restrict__ qb, short* __restrict__ kb, short* __restrict__ vtb,
    float* __restrict__ outb,
    int M, int N, int K) {
  constexpr int BK = 32;
  __shared__ short As[128 * BK];
  __shared__ short Bs[128 * BK];

  int tid  = threadIdx.x;
  int lane = tid & 63;
  int wv   = tid >> 6;
  int q15  = lane & 15, g = lane >> 4;
  int ntn  = N >> 7;
  int bm   = blockIdx.x / ntn;
  int bn   = blockIdx.x % ntn;
  int row0 = bm << 7, col0 = bn << 7;
  int wm   = (wv >> 1) << 6;
  int wn   = (wv & 1) << 6;

  f32x4 acc[4][4];
#pragma unroll
  for (int i = 0; i < 4; i++)
#pragma unroll
    for (int j = 0; j < 4; j++) acc[i][j] = (f32x4){0.f, 0.f, 0.f, 0.f};

  const short* ag = A  + (size_t)(row0 + (tid >> 2)) * K + (tid & 3) * 8;
  const short* bg = Bt + (size_t)(col0 + (tid >> 2)) * K + (tid & 3) * 8;
  short* as = As + tid * 8;
  short* bs = Bs + tid * 8;
  const size_t gstep = (size_t)64 * K;

  for (int k0 = 0; k0 < K; k0 += BK) {
    __syncthreads();
    gld_lds16(as, ag);
    gld_lds16(as + 64 * BK, ag + gstep);
    gld_lds16(bs, bg);
    gld_lds16(bs + 64 * BK, bg + gstep);
    __syncthreads();

    short8 af[4], bf[4];
#pragma unroll
    for (int mi = 0; mi < 4; mi++)
      af[mi] = *reinterpret_cast<const short8*>(&As[(wm + mi * 16 + q15) * BK + g * 8]);
#pragma unroll
    for (int ni = 0; ni < 4; ni++)
      bf[ni] = *reinterpret_cast<const short8*>(&Bs[(wn + ni * 16 + q15) * BK + g * 8]);
    __builtin_amdgcn_s_setprio(1);
#pragma unroll
    for (int mi = 0; mi < 4; mi++)
#pragma unroll
      for (int ni = 0; ni < 4; ni++)
        acc[mi][ni] = __builtin_amdgcn_mfma_f32_16x16x32_bf16(af[mi], bf[ni],
                                                              acc[mi][ni], 0, 0, 0);
    __builtin_amdgcn_s_setprio(0);
    ag += BK;
    bg += BK;
  }

  // epilogue: C/D layout: col = lane&15, row = (lane>>4)*4 + r
#pragma unroll
  for (int mi = 0; mi < 4; mi++) {
#pragma unroll
    for (int ni = 0; ni < 4; ni++) {
      int rb  = row0 + wm + mi * 16 + (g << 2);
      int col = col0 + wn + ni * 16 + q15;
      f32x4 v = acc[mi][ni];
      if (MODE == 0) {
        int proj = col >> 10;
        int hh   = (col >> 6) & (H_NUM - 1);
        int d    = col & (D_HEAD - 1);
        int b    = rb >> 11;
        int t    = rb & (T_SEQ - 1);
        if (proj < 2) {
          float scl = (proj == 0) ? 0.125f : 1.0f;  // fold 1/sqrt(D) into q
          short* dst = (proj == 0 ? qb : kb) +
                       ((size_t)(b * H_NUM + hh) * T_SEQ) * D_HEAD + d;
#pragma unroll
          for (int r = 0; r < 4; r++)
            dst[(size_t)(t + r) * D_HEAD] = f2bf(v[r] * scl);
        } else {
          short4v pk;
#pragma unroll
          for (int r = 0; r < 4; r++) pk[r] = f2bf(v[r]);
          short* dst = vtb + ((size_t)(b * H_NUM + hh) * D_HEAD + d) * T_SEQ + t;
          *reinterpret_cast<short4v*>(dst) = pk;
        }
      } else {
        float bb = bias[col];
#pragma unroll
        for (int r = 0; r < 4; r++)
          outb[(size_t)(rb + r) * N + col] = v[r] + bb;
      }
    }
  }
}

// ---------------------------------------------------------------------------
// Flash attention v6: swapped-operand (S^T = K·Q^T), LDS-staged K/V chunks
// (double-buffered global_load_lds w=16, pre-swizzled source + swizzled
// ds_read), PLUS causal strip-pairing for perfect load balance:
//   32 strips of 64 q; block pairIdx i handles strips i and 31-i.
//   Each wave: qt0 = 16 q of strip i, qt1 = 16 q of strip 31-i.
//   Per-wave work = (i+1) + (32-i) = 33 qt-chunks, constant over all blocks.
// Grid = 512 identical-work blocks (2/CU), XCD-local per head.
// ---------------------------------------------------------------------------
__global__ __launch_bounds__(256) void attn_fwd(const short* __restrict__ qg,
                                                const short* __restrict__ kg,
                                                const short* __restrict__ vt,
                                                short* __restrict__ ob) {
  constexpr float LOG2E = 1.44269504f;
  int bid  = blockIdx.x;
  int slot = bid >> 3;                  // 0..63
  int bh   = (bid & 7) * 4 + (slot & 3);
  int ip   = slot >> 2;                 // pair index 0..15
  int b    = bh >> 4;
  int h    = bh & 15;
  int tid  = threadIdx.x, lane = tid & 63, wv = tid >> 6;
  int q15  = lane & 15, g = lane >> 4;
  int qr0  = ip * 64 + wv * 16;               // strip i    (light)
  int qr1  = (31 - ip) * 64 + wv * 16;        // strip 31-i (heavy)

  __shared__ short Kl[2][64 * 64];      // [s][d] swizzled, 8KB per buf
  __shared__ short Vl[2][64 * 64];      // [d][s] swizzled
  __shared__ short Ol[4][32][68];       // epilogue transpose

  const short* qp = qg + (size_t)bh * T_SEQ * D_HEAD;
  const short* kp = kg + (size_t)bh * T_SEQ * D_HEAD;
  const short* vp = vt + (size_t)bh * D_HEAD * T_SEQ;

  // staging geometry (rule #21): LDS written linearly (base + lane*16B);
  // SOURCE colbyte pre-swizzled so data(row, cb) lands at byte row*128 ^ ((row&7)<<4).
  int r8    = lane >> 3;
  int gcb   = ((lane & 7) * 16) ^ (r8 << 4);
  int srow0 = wv * 16;

  // fragment-read offsets (chunk-invariant, shorts)
  int hh = (q15 & 7) << 4;
  int koff0 = ((0 * 64 + g * 16) ^ hh) >> 1;
  int koff1 = ((1 * 64 + g * 16) ^ hh) >> 1;
  int voff[4];
#pragma unroll
  for (int st = 0; st < 4; st++) voff[st] = ((st * 32 + g * 8) ^ hh) >> 1;

  // Q fragments (prescaled by 1/8): lane&15 = q, elems over d
  short8 qf0[2], qf1[2];
#pragma unroll
  for (int kk = 0; kk < 2; kk++) {
    qf0[kk] = *reinterpret_cast<const short8*>(
        qp + (size_t)(qr0 + q15) * D_HEAD + kk * 32 + g * 8);
    qf1[kk] = *reinterpret_cast<const short8*>(
        qp + (size_t)(qr1 + q15) * D_HEAD + kk * 32 + g * 8);
  }

  f32x4 acc0[4], acc1[4];
#pragma unroll
  for (int dt = 0; dt < 4; dt++) {
    acc0[dt] = (f32x4){0.f, 0.f, 0.f, 0.f};
    acc1[dt] = (f32x4){0.f, 0.f, 0.f, 0.f};
  }
  float m0 = -1e30f, l0 = 0.f, m1 = -1e30f, l1 = 0.f;

  int nch = 32 - ip;  // chunks 0..31-ip (qt1's range; superset of qt0's)

  auto stage = [&](int c, int pb) {
    const short* ks = kp + (size_t)(c * 64 + srow0 + r8) * D_HEAD + (gcb >> 1);
    const short* vs = vp + (size_t)(srow0 + r8) * T_SEQ + c * 64 + (gcb >> 1);
    short* kd = &Kl[pb][srow0 * 64] + lane * 8;
    short* vd = &Vl[pb][srow0 * 64] + lane * 8;
    gld_lds16(kd, ks);
    gld_lds16(kd + 8 * 64, ks + (size_t)8 * D_HEAD);
    gld_lds16(vd, vs);
    gld_lds16(vd + 8 * 64, vs + (size_t)8 * T_SEQ);
  };

  // one q-tile's S / softmax / PV for the current chunk (all static indices)
  auto do_tile = [&](short8 (&qfx)[2], f32x4 (&accx)[4], float& mref, float& lref,
                     int qrX, bool masked, int s0,
                     short8 (&kf)[4][2], short4v (&vf)[4][4]) {
    f32x4 sv[4];
    __builtin_amdgcn_s_setprio(1);
#pragma unroll
    for (int st = 0; st < 4; st++) {
      f32x4 s = (f32x4){0.f, 0.f, 0.f, 0.f};
      s = __builtin_amdgcn_mfma_f32_16x16x32_bf16(kf[st][0], qfx[0], s, 0, 0, 0);
      s = __builtin_amdgcn_mfma_f32_16x16x32_bf16(kf[st][1], qfx[1], s, 0, 0, 0);
      sv[st] = s;
    }
    __builtin_amdgcn_s_setprio(0);

    if (masked) {
#pragma unroll
      for (int st = 0; st < 4; st++)
#pragma unroll
        for (int r = 0; r < 4; r++) {
          int sg = s0 + st * 16 + g * 4 + r;
          if (sg > qrX + q15) sv[st][r] = -1e30f;
        }
    }

    float mx = sv[0][0];
#pragma unroll
    for (int st = 0; st < 4; st++)
#pragma unroll
      for (int r = 0; r < 4; r++) mx = fmaxf(mx, sv[st][r]);
    mx = fmaxf(mx, __shfl_xor(mx, 16));
    mx = fmaxf(mx, __shfl_xor(mx, 32));
    if (!__all(mx <= mref + 8.0f)) {  // defer-max (T13)
      float mnew = fmaxf(mref, mx);
      float sc   = __builtin_amdgcn_exp2f((mref - mnew) * LOG2E);
      mref = mnew;
      lref *= sc;
#pragma unroll
      for (int dt = 0; dt < 4; dt++) accx[dt] *= sc;
    }
    float mcur = mref;
    short4v pbf[4];
    float ps = 0.f;
#pragma unroll
    for (int st = 0; st < 4; st++)
#pragma unroll
      for (int r = 0; r < 4; r++) {
        float p = __builtin_amdgcn_exp2f((sv[st][r] - mcur) * LOG2E);
        ps += p;
        pbf[st][r] = f2bf(p);
      }
    ps += __shfl_xor(ps, 16);
    ps += __shfl_xor(ps, 32);
    lref += ps;

    __builtin_amdgcn_s_setprio(1);
#pragma unroll
    for (int st = 0; st < 4; st++)
#pragma unroll
      for (int dt = 0; dt < 4; dt++) {
#if __has_builtin(__builtin_amdgcn_mfma_f32_16x16x16bf16_1k)
        accx[dt] = __builtin_amdgcn_mfma_f32_16x16x16bf16_1k(
            vf[st][dt], pbf[st], accx[dt], 0, 0, 0);
#else
        short4v v4 = vf[st][dt];
        short4v p4 = pbf[st];
        short8 az = (short8){v4[0], v4[1], v4[2], v4[3], 0, 0, 0, 0};
        short8 bz = (short8){p4[0], p4[1], p4[2], p4[3], 0, 0, 0, 0};
        accx[dt] =
            __builtin_amdgcn_mfma_f32_16x16x32_bf16(az, bz, accx[dt], 0, 0, 0);
#endif
      }
    __builtin_amdgcn_s_setprio(0);
  };

  stage(0, 0);
  __syncthreads();

  for (int c = 0; c < nch; ++c) {
    int s0 = c * 64;
    int pb = c & 1;
    if (c + 1 < nch) stage(c + 1, pb ^ 1);

    // shared K/V fragments for both q-tiles
    short8 kf[4][2];
#pragma unroll
    for (int st = 0; st < 4; st++) {
      int rbase = (st * 16 + q15) * 64;
      kf[st][0] = *reinterpret_cast<const short8*>(&Kl[pb][rbase + koff0]);
      kf[st][1] = *reinterpret_cast<const short8*>(&Kl[pb][rbase + koff1]);
    }
    short4v vf[4][4];
#pragma unroll
    for (int st = 0; st < 4; st++)
#pragma unroll
      for (int dt = 0; dt < 4; dt++)
        vf[st][dt] = *reinterpret_cast<const short4v*>(
            &Vl[pb][(dt * 16 + q15) * 64 + voff[st]]);

    do_tile(qf1, acc1, m1, l1, qr1, c == nch - 1, s0, kf, vf);   // heavy strip
    if (c <= ip) do_tile(qf0, acc0, m0, l0, qr0, c == ip, s0, kf, vf);  // light

    __syncthreads();
  }

  // epilogue: per-wave LDS transpose -> coalesced bf16 stores (two strips)
#pragma unroll
  for (int dt = 0; dt < 4; dt++) {
    float i0 = 1.0f / l0, i1 = 1.0f / l1;
#pragma unroll
    for (int r = 0; r < 4; r++) {
      Ol[wv][q15][dt * 16 + g * 4 + r]      = f2bf(acc0[dt][r] * i0);
      Ol[wv][16 + q15][dt * 16 + g * 4 + r] = f2bf(acc1[dt][r] * i1);
    }
  }
  __syncthreads();
  int row = lane >> 1, cb = (lane & 1) * 32;
  int grow = (row < 16) ? (qr0 + row) : (qr1 + row - 16);
  size_t base = ((size_t)(b * T_SEQ) + grow) * C_DIM + h * 64 + cb;
#pragma unroll
  for (int i = 0; i < 4; i++)
    *reinterpret_cast<short8*>(ob + base + i * 8) =
        *reinterpret_cast<const short8*>(&Ol[wv][row][cb + i * 8]);
}

// ---------------------------------------------------------------------------
// Launch. Workspace layout (needs >= 40 MB):
//   [0, 8M)        xb   bf16 x cast            (reused as obuf after QKV GEMM)
//   [8M, 14.3M)    Wt   bf16 packed QKV weights [3072][1024]
//   [14M, 16M)     Wob  bf16 Wo [1024][1024]
//   [16M, 24M)     qb   bf16 [B,H,T,D]  (prescaled by 1/8)
//   [24M, 32M)     kb   bf16 [B,H,T,D]
//   [32M, 40M)     vtb  bf16 [B,H,D,T]
// ---------------------------------------------------------------------------
extern "C" void kernel_launch(void* const* d_in, const int* in_sizes, int n_in,
                              void* d_out, int out_size, void* d_ws, size_t ws_size,
                              hipStream_t stream) {
  const float* x  = (const float*)d_in[0];
  const float* Wq = (const float*)d_in[1];
  const float* Wk = (const float*)d_in[2];
  const float* Wv = (const float*)d_in[3];
  const float* Wo = (const float*)d_in[4];
  const float* bo = (const float*)d_in[5];
  float* out = (float*)d_out;

  char* ws = (char*)d_ws;
  short* xb   = (short*)(ws + 0);
  short* Wt   = (short*)(ws + 8388608);
  short* Wob  = (short*)(ws + 14680064);
  short* qb   = (short*)(ws + 16777216);
  short* kb   = (short*)(ws + 25165824);
  short* vtb  = (short*)(ws + 33554432);
  short* obuf = xb;  // reuse after QKV GEMM consumed xb

  cvt_f32_bf16<<<2048, 256, 0, stream>>>(x, xb, M_ROWS * C_DIM / 8);
  cvt_f32_bf16<<<512, 256, 0, stream>>>(Wo, Wob, C_DIM * C_DIM / 8);
  pack_w<<<768, 256, 0, stream>>>(Wq, Wk, Wv, Wt);

  gemm_bt<0><<<(M_ROWS / 128) * (N_QKV / 128), 256, 0, stream>>>(
      xb, Wt, nullptr, qb, kb, vtb, nullptr, M_ROWS, N_QKV, C_DIM);

  attn_fwd<<<512, 256, 0, stream>>>(qb, kb, vtb, obuf);

  gemm_bt<1><<<(M_ROWS / 128) * (C_DIM / 128), 256, 0, stream>>>(
      obuf, Wob, bo, nullptr, nullptr, nullptr, out, M_ROWS, C_DIM, C_DIM);
}